// Round 4
// baseline (56.273 us; speedup 1.0000x reference)
//
#include <hip/hip_runtime.h>
#include <hip/hip_cooperative_groups.h>

namespace cg = cooperative_groups;

// B=4, N=512, D=64, Dm=64, Do=64. Single cooperative kernel, 256 blocks x 1024 thr.
// Phase 1 (tid<512, (r,m)=tid/64,tid%64; 8 rows/block):
//   a_s[r][m] = b_msg[m] + sum_d V[row][d]*Wi[m][d]          (LDS, block-local)
//   C[row][m] = mask[row] ? sum_d V[row][d]*Wj[m][d] : -1e30 (global; bakes j-mask)
//   o1(reg)   = b_node[m] + sum_d V[row][d]*Wn[m][d]         (V-half of node GEMM)
// grid sync (C all-to-all within batch)
// Phase 2 (all 1024 thr: m=tid%64, jc=tid/64 owns 8 j's per 128-j tile, 8 rows in regs):
//   agg[r][m] = mask ? sum_j relu(a + C[b][j][m]) : 0
//   out[row][m] = relu(o1 + sum_k agg[r][k]*Wn[m][64+k])

typedef float v2f __attribute__((ext_vector_type(2)));

__device__ __forceinline__ v2f pk_add(v2f a, v2f b) {
    v2f d;
    asm("v_pk_add_f32 %0, %1, %2" : "=v"(d) : "v"(a), "v"(b));
    return d;
}

__global__ __launch_bounds__(1024) void fused_graphblock(
    const float* __restrict__ V, const int* __restrict__ mask,
    const float* __restrict__ Wmsg, const float* __restrict__ bmsg,
    const float* __restrict__ Wn, const float* __restrict__ bn,
    float* __restrict__ C, float* __restrict__ out)
{
    // overlay: phase1 { wm[64][132] @0 (8448), wn1[64][68] @8448 (4352) }
    //          phase2 { ctile[128][64] @0 (8192), wn2[64][68] @8448 (4352) }
    __shared__ float buf[12800];         // 51.2 KB
    __shared__ float a_s[512];
    __shared__ float agg_s[512];

    int tid = threadIdx.x;
    int i0  = blockIdx.x * 8;
    int b   = blockIdx.x >> 6;           // 64 blocks per batch (N=512, 8 rows/block)

    float* wm  = buf;                    // stride 132 (pad: bank (4m+d)%32, conflict-free)
    float* wn1 = buf + 8448;             // stride 68

    // ---- phase 1 staging (coalesced float4 global -> padded LDS) ----
#pragma unroll
    for (int k = 0; k < 2; ++k) {
        int f4 = tid + k * 1024;         // 0..2047
        int mm = f4 >> 5, dd = (f4 & 31) << 2;
        *(float4*)&wm[mm * 132 + dd] = ((const float4*)Wmsg)[f4];
    }
    {
        int oo = tid >> 4, kk = (tid & 15) << 2;
        *(float4*)&wn1[oo * 68 + kk] = *(const float4*)&Wn[oo * 128 + kk];
    }
    __syncthreads();

    float o1 = 0.f;
    int   mk = 0;
    if (tid < 512) {
        int m = tid & 63;
        int row = __builtin_amdgcn_readfirstlane(i0 + (tid >> 6));  // wave-uniform
        const float* v = V + row * 64;                              // -> scalar loads
        float sa = bmsg[m], sc = 0.f, so = bn[m];
#pragma unroll
        for (int d0 = 0; d0 < 64; d0 += 4) {
            float4 va = *(const float4*)&v[d0];
            float4 wa = *(float4*)&wm[m * 132 + d0];
            float4 wc = *(float4*)&wm[m * 132 + 64 + d0];
            float4 wo = *(float4*)&wn1[m * 68 + d0];
            sa = fmaf(va.x, wa.x, sa); sa = fmaf(va.y, wa.y, sa);
            sa = fmaf(va.z, wa.z, sa); sa = fmaf(va.w, wa.w, sa);
            sc = fmaf(va.x, wc.x, sc); sc = fmaf(va.y, wc.y, sc);
            sc = fmaf(va.z, wc.z, sc); sc = fmaf(va.w, wc.w, sc);
            so = fmaf(va.x, wo.x, so); so = fmaf(va.y, wo.y, so);
            so = fmaf(va.z, wo.z, so); so = fmaf(va.w, wo.w, so);
        }
        mk = mask[row];
        a_s[tid] = sa;
        C[row * 64 + m] = mk ? sc : -1e30f;   // relu(a-1e30)=0 bakes the j-mask
        o1 = so;
    }

    cg::this_grid().sync();                   // C visible device-wide

    // ---- phase 2 ----
    float* ctile = buf;                       // [128][64]
    float* wn2   = buf + 8448;                // stride 68
    {
        int oo = tid >> 4, kk = (tid & 15) << 2;
        *(float4*)&wn2[oo * 68 + kk] = *(const float4*)&Wn[oo * 128 + 64 + kk];
    }

    int m  = tid & 63;
    int jc = tid >> 6;                        // 0..15: owns j = jc*8 .. jc*8+7 of each tile
    v2f ad[8], acc[8];
#pragma unroll
    for (int r = 0; r < 8; ++r) {
        float a = a_s[r * 64 + m];
        ad[r]  = (v2f){a, a};
        acc[r] = (v2f){0.f, 0.f};
    }

    const float* cb = C + (size_t)b * 512 * 64;
    for (int j0 = 0; j0 < 512; j0 += 128) {
        __syncthreads();
        const float4* src = (const float4*)(cb + (size_t)j0 * 64);
        float4* dst = (float4*)ctile;
        dst[tid]        = src[tid];
        dst[tid + 1024] = src[tid + 1024];
        __syncthreads();
        const float* cbase = ctile + jc * 512 + m;
#pragma unroll
        for (int p = 0; p < 4; ++p) {
            v2f c2 = {cbase[p * 128], cbase[p * 128 + 64]};   // j pair (jc*8+2p, +1)
#pragma unroll
            for (int r = 0; r < 8; ++r) {
                v2f x = pk_add(ad[r], c2);
                x.x = fmaxf(x.x, 0.f);
                x.y = fmaxf(x.y, 0.f);
                acc[r] = pk_add(acc[r], x);
            }
        }
    }
    __syncthreads();                          // ctile consumed; reuse as part[16][8][64]
#pragma unroll
    for (int r = 0; r < 8; ++r)
        ctile[jc * 512 + r * 64 + m] = acc[r].x + acc[r].y;
    __syncthreads();

    if (tid < 512) {
        int r = tid >> 6;
        float aggsum = 0.f;
#pragma unroll
        for (int q = 0; q < 16; ++q) aggsum += ctile[q * 512 + r * 64 + m];
        agg_s[tid] = mk ? aggsum : 0.f;       // mk from phase 1, same (r,m) mapping
    }
    __syncthreads();
    if (tid < 512) {
        int r = tid >> 6;
        float s = o1;                         // o1 from phase 1, same mapping
#pragma unroll
        for (int k = 0; k < 64; k += 4) {
            float4 h4 = *(float4*)&agg_s[r * 64 + k];   // wave-uniform broadcast
            float4 w4 = *(float4*)&wn2[m * 68 + k];
            s = fmaf(h4.x, w4.x, s); s = fmaf(h4.y, w4.y, s);
            s = fmaf(h4.z, w4.z, s); s = fmaf(h4.w, w4.w, s);
        }
        out[(i0 + r) * 64 + m] = fmaxf(s, 0.f);
    }
}

extern "C" void kernel_launch(void* const* d_in, const int* in_sizes, int n_in,
                              void* d_out, int out_size, void* d_ws, size_t ws_size,
                              hipStream_t stream) {
    const float* V    = (const float*)d_in[0];
    const int*   mask = (const int*)d_in[1];
    const float* Wmsg = (const float*)d_in[2];
    const float* bmsg = (const float*)d_in[3];
    const float* Wn   = (const float*)d_in[4];
    const float* bn   = (const float*)d_in[5];
    float* outp = (float*)d_out;

    const int BN = in_sizes[1];              // 2048
    float* C = (float*)d_ws;                 // BN*64 floats

    void* args[] = { (void*)&V, (void*)&mask, (void*)&Wmsg, (void*)&bmsg,
                     (void*)&Wn, (void*)&bn, (void*)&C, (void*)&outp };
    hipLaunchCooperativeKernel((const void*)fused_graphblock,
                               dim3(BN / 8), dim3(1024), args, 0, stream);
}

// Round 5
// 32.763 us; speedup vs baseline: 1.7176x; 1.7176x over previous
//
#include <hip/hip_runtime.h>

// B=4, N=512, D=64, Dm=64, Do=64. ONE regular kernel, 256 blocks x 1024 thr
// (co-residency at 1 block/CU proven by round-4 cooperative launch passing),
// plus a 128-B memsetAsync node to zero the barrier counter each call.
//
// Phase 1 (tid<512, (r,m)=(tid/64,tid%64), 8 rows/block):
//   a_s[r][m] = b_msg[m] + sum_d V[row][d]*Wi[m][d]           (LDS)
//   C[row][m] = mask[row] ? sum_d V[row][d]*Wj[m][d] : -1e30  (global; bakes j-mask)
//   o1 (reg)  = b_node[m] + sum_d V[row][d]*Wn[m][d]
// manual device-scope grid barrier (C all-to-all within batch)
// Phase 2 (all 1024 thr: m=tid%64, jc=tid/64 owns 8 j per 128-j tile, 8 rows in regs):
//   relu(a+c) = max(c,-a)+a  ->  agg = sum_j max(c_j,-a) + 512*a  (masked j: c=-1e30 -> 0)
//   out[row][m] = relu(o1 + sum_k agg[r][k]*Wn[m][64+k])

typedef float v2f __attribute__((ext_vector_type(2)));

__device__ __forceinline__ v2f pk_add(v2f a, v2f b) {
    v2f d;
    asm("v_pk_add_f32 %0, %1, %2" : "=v"(d) : "v"(a), "v"(b));
    return d;
}

__global__ __launch_bounds__(1024) void fused_graphblock(
    const float* __restrict__ V, const int* __restrict__ mask,
    const float* __restrict__ Wmsg, const float* __restrict__ bmsg,
    const float* __restrict__ Wn, const float* __restrict__ bn,
    float* __restrict__ C, unsigned int* __restrict__ ctr,
    float* __restrict__ out)
{
    // overlay: phase1 { wm[64][132] @0 (8448 f), wn1[64][68] @8448 }
    //          phase2 { ctile[128][64] @0 (8192 f), wn2[64][68] @8448 }
    __shared__ float buf[12800];         // 51.2 KB
    __shared__ float a_s[512];
    __shared__ float agg_s[512];

    int tid = threadIdx.x;
    int i0  = blockIdx.x * 8;
    int b   = blockIdx.x >> 6;           // 64 blocks per batch

    float* wm  = buf;                    // stride 132
    float* wn1 = buf + 8448;             // stride 68

    // ---- phase 1 staging ----
#pragma unroll
    for (int k = 0; k < 2; ++k) {
        int f4 = tid + k * 1024;
        int mm = f4 >> 5, dd = (f4 & 31) << 2;
        *(float4*)&wm[mm * 132 + dd] = ((const float4*)Wmsg)[f4];
    }
    {
        int oo = tid >> 4, kk = (tid & 15) << 2;
        *(float4*)&wn1[oo * 68 + kk] = *(const float4*)&Wn[oo * 128 + kk];
    }
    __syncthreads();

    float o1 = 0.f;
    int   mk = 0;
    if (tid < 512) {
        int m = tid & 63;
        int row = __builtin_amdgcn_readfirstlane(i0 + (tid >> 6));  // wave-uniform
        const float* v = V + row * 64;
        float sa = bmsg[m], sc = 0.f, so = bn[m];
#pragma unroll
        for (int d0 = 0; d0 < 64; d0 += 4) {
            float4 va = *(const float4*)&v[d0];
            float4 wa = *(float4*)&wm[m * 132 + d0];
            float4 wc = *(float4*)&wm[m * 132 + 64 + d0];
            float4 wo = *(float4*)&wn1[m * 68 + d0];
            sa = fmaf(va.x, wa.x, sa); sa = fmaf(va.y, wa.y, sa);
            sa = fmaf(va.z, wa.z, sa); sa = fmaf(va.w, wa.w, sa);
            sc = fmaf(va.x, wc.x, sc); sc = fmaf(va.y, wc.y, sc);
            sc = fmaf(va.z, wc.z, sc); sc = fmaf(va.w, wc.w, sc);
            so = fmaf(va.x, wo.x, so); so = fmaf(va.y, wo.y, so);
            so = fmaf(va.z, wo.z, so); so = fmaf(va.w, wo.w, so);
        }
        mk = mask[row];
        a_s[tid] = sa;
        C[row * 64 + m] = mk ? sc : -1e30f;
        o1 = so;
    }

    // ---- manual grid barrier (device/agent scope) ----
    __syncthreads();                                  // block's C stores drained (vmcnt0 before s_barrier)
    if (tid == 0) {
        __builtin_amdgcn_fence(__ATOMIC_RELEASE, "agent");
        __hip_atomic_fetch_add(ctr, 1u, __ATOMIC_RELAXED, __HIP_MEMORY_SCOPE_AGENT);
        unsigned int spins = 0;
        while (__hip_atomic_load(ctr, __ATOMIC_RELAXED, __HIP_MEMORY_SCOPE_AGENT) < 256u) {
            __builtin_amdgcn_s_sleep(2);
            if (++spins > (1u << 25)) break;          // failsafe: clean wrong-answer, not a hang
        }
        __builtin_amdgcn_fence(__ATOMIC_ACQUIRE, "agent");
    }
    __syncthreads();

    // ---- phase 2 ----
    float* ctile = buf;                  // [128][64]
    float* wn2   = buf + 8448;           // stride 68
    {
        int oo = tid >> 4, kk = (tid & 15) << 2;
        *(float4*)&wn2[oo * 68 + kk] = *(const float4*)&Wn[oo * 128 + 64 + kk];
    }

    int m  = tid & 63;
    int jc = tid >> 6;                   // 0..15
    float ar[8], nar[8];
    v2f acc[8];
#pragma unroll
    for (int r = 0; r < 8; ++r) {
        ar[r]  = a_s[r * 64 + m];
        nar[r] = -ar[r];
        acc[r] = (v2f){0.f, 0.f};
    }

    const float* cb = C + (size_t)b * 512 * 64;
    for (int j0 = 0; j0 < 512; j0 += 128) {
        __syncthreads();
        const float4* src = (const float4*)(cb + (size_t)j0 * 64);
        float4* dst = (float4*)ctile;
        dst[tid]        = src[tid];
        dst[tid + 1024] = src[tid + 1024];
        __syncthreads();
        const float* cbase = ctile + jc * 512 + m;
#pragma unroll
        for (int p = 0; p < 4; ++p) {
            v2f c2 = {cbase[p * 128], cbase[p * 128 + 64]};   // j pair
#pragma unroll
            for (int r = 0; r < 8; ++r) {
                v2f mx;
                mx.x = fmaxf(c2.x, nar[r]);        // max(c,-a): masked c=-1e30 -> -a -> net 0
                mx.y = fmaxf(c2.y, nar[r]);
                acc[r] = pk_add(acc[r], mx);
            }
        }
    }
    __syncthreads();                     // ctile consumed; reuse as part[16][8][64]
#pragma unroll
    for (int r = 0; r < 8; ++r)
        ctile[jc * 512 + r * 64 + m] = acc[r].x + acc[r].y;
    __syncthreads();

    if (tid < 512) {
        int r = tid >> 6;
        float aggsum = 0.f;
#pragma unroll
        for (int q = 0; q < 16; ++q) aggsum += ctile[q * 512 + r * 64 + m];
        aggsum = fmaf(512.f, ar[r == (tid >> 6) ? r : r], aggsum);  // + 512*a  (see below)
        agg_s[tid] = mk ? aggsum : 0.f;
    }
    __syncthreads();
    if (tid < 512) {
        int r = tid >> 6;
        float s = o1;
#pragma unroll
        for (int k = 0; k < 64; k += 4) {
            float4 h4 = *(float4*)&agg_s[r * 64 + k];   // wave-uniform broadcast
            float4 w4 = *(float4*)&wn2[m * 68 + k];
            s = fmaf(h4.x, w4.x, s); s = fmaf(h4.y, w4.y, s);
            s = fmaf(h4.z, w4.z, s); s = fmaf(h4.w, w4.w, s);
        }
        out[(i0 + r) * 64 + m] = fmaxf(s, 0.f);
    }
}

extern "C" void kernel_launch(void* const* d_in, const int* in_sizes, int n_in,
                              void* d_out, int out_size, void* d_ws, size_t ws_size,
                              hipStream_t stream) {
    const float* V    = (const float*)d_in[0];
    const int*   mask = (const int*)d_in[1];
    const float* Wmsg = (const float*)d_in[2];
    const float* bmsg = (const float*)d_in[3];
    const float* Wn   = (const float*)d_in[4];
    const float* bn   = (const float*)d_in[5];
    float* outp = (float*)d_out;

    const int BN = in_sizes[1];          // 2048
    float* C = (float*)d_ws;             // BN*64 floats = 512 KB
    unsigned int* ctr = (unsigned int*)((char*)d_ws + (1 << 20));

    hipMemsetAsync(ctr, 0, 128, stream);
    fused_graphblock<<<dim3(BN / 8), dim3(1024), 0, stream>>>(
        V, mask, Wmsg, bmsg, Wn, bn, C, ctr, outp);
}

// Round 6
// 19.940 us; speedup vs baseline: 2.8222x; 1.6431x over previous
//
#include <hip/hip_runtime.h>
#include <hip/hip_bf16.h>

// B=4, N=512, D=64. ONE kernel, 256 blocks x 1024 thr, no inter-block deps:
// each block (8 i-rows) recomputes the c-values it needs (full 512-j column
// block of its batch) on the fly via bf16 hi/lo split MFMA (3-term, ~fp32 acc).
//
// P1:  a_s[r][m] = b_msg[m] + V[row]·Wi[m];  o1(reg) = b_node[m] + V[row]·Wn1[m]
// loop 8 j-tiles (64 j): vt = bf16split(V[tile]);  c[j][m] = MFMA(Wj, vt) (masked j -> -1e30)
//      jacc[r] += sum_j max(c[j][m], -a)          (relu(a+c) = max(c,-a)+a)
// epi: agg = sum_parts + 512*a; out = relu(o1 + agg·Wn2)

typedef float v2f  __attribute__((ext_vector_type(2)));
typedef float f32x4 __attribute__((ext_vector_type(4)));
typedef short bf16x8 __attribute__((ext_vector_type(8)));
typedef unsigned short u16;
typedef unsigned short u16x4 __attribute__((ext_vector_type(4)));

__device__ __forceinline__ v2f pk_add(v2f a, v2f b) {
    v2f d; asm("v_pk_add_f32 %0, %1, %2" : "=v"(d) : "v"(a), "v"(b)); return d;
}

__device__ __forceinline__ void split4(float4 v, u16x4& h, u16x4& l) {
    float vv[4] = {v.x, v.y, v.z, v.w};
#pragma unroll
    for (int i = 0; i < 4; ++i) {
        __hip_bfloat16 bh = __float2bfloat16(vv[i]);
        float r = vv[i] - __bfloat162float(bh);
        __hip_bfloat16 bl = __float2bfloat16(r);
        h[i] = *(u16*)&bh;
        l[i] = *(u16*)&bl;
    }
}

// LDS (floats): region0 @0 (8960): P1 wm[64][132] | P2 vtH/vtL u16[64][72] (4608f) + c[64][68] @4608 | P3 part[16][8][64]
//               region1 @8960 (4608): P1 wn1[64][68] | P2 wjH/wjL u16[64][72] | P3 wn2[64][68]
//               mask_s @13568 (512 int) | a_s @14080 | agg_s @14592   -> 15104 f = 60416 B
__global__ __launch_bounds__(1024) void fused_gb(
    const float* __restrict__ V, const int* __restrict__ mask,
    const float* __restrict__ Wmsg, const float* __restrict__ bmsg,
    const float* __restrict__ Wn, const float* __restrict__ bn,
    float* __restrict__ out)
{
    __shared__ float buf[15104];
    float* wm   = buf;                       // [64][132] f32
    float* wn1  = buf + 8960;                // [64][68]  f32
    u16*   wjH  = (u16*)(buf + 8960);        // [64][72]  bf16
    u16*   wjL  = (u16*)(buf + 8960 + 2304);
    u16*   vtH  = (u16*)buf;                 // [64][72]  bf16
    u16*   vtL  = (u16*)(buf + 2304);
    float* cbuf = buf + 4608;                // [64][68]  f32
    float* part = buf;                       // [16][8][64]
    float* wn2  = buf + 8960;                // [64][68]  f32
    int*   mask_s = (int*)(buf + 13568);
    float* a_s  = buf + 14080;
    float* agg_s= buf + 14592;

    int tid  = threadIdx.x;
    int lane = tid & 63;
    int b    = blockIdx.x >> 6;              // batch (64 blocks per batch)
    int i0   = blockIdx.x * 8;               // global row base
    const float* Vb = V + (size_t)b * 512 * 64;

    // ---- P1 staging ----
#pragma unroll
    for (int k = 0; k < 2; ++k) {
        int f4 = tid + k * 1024;
        int mm = f4 >> 5, dd = (f4 & 31) << 2;
        *(float4*)&wm[mm * 132 + dd] = ((const float4*)Wmsg)[f4];
    }
    {
        int oo = tid >> 4, kk = (tid & 15) << 2;
        *(float4*)&wn1[oo * 68 + kk] = *(const float4*)&Wn[oo * 128 + kk];
    }
    if (tid < 512) mask_s[tid] = mask[b * 512 + tid];
    __syncthreads();

    // ---- P1 compute: a, o1 for own 8 rows (tid<512) ----
    float o1 = 0.f;
    int   mk = 0;
    if (tid < 512) {
        int m = tid & 63;
        int row = __builtin_amdgcn_readfirstlane(i0 + (tid >> 6));  // wave-uniform
        const float* v = V + row * 64;
        float sa = bmsg[m], so = bn[m];
#pragma unroll
        for (int d0 = 0; d0 < 64; d0 += 4) {
            float4 va = *(const float4*)&v[d0];
            float4 wa = *(float4*)&wm[m * 132 + d0];
            float4 wo = *(float4*)&wn1[m * 68 + d0];
            sa = fmaf(va.x, wa.x, sa); sa = fmaf(va.y, wa.y, sa);
            sa = fmaf(va.z, wa.z, sa); sa = fmaf(va.w, wa.w, sa);
            so = fmaf(va.x, wo.x, so); so = fmaf(va.y, wo.y, so);
            so = fmaf(va.z, wo.z, so); so = fmaf(va.w, wo.w, so);
        }
        mk = mask_s[(blockIdx.x & 63) * 8 + (tid >> 6)];
        a_s[tid] = sa;
        o1 = so;
    }
    __syncthreads();

    // ---- convert Wj (wm cols 64..127) -> bf16 hi/lo planes (overwrites wn1) ----
    {
        int m = tid >> 4, k0 = (tid & 15) << 2;
        float4 wv = *(float4*)&wm[m * 132 + 64 + k0];
        u16x4 h, l; split4(wv, h, l);
        *(u16x4*)&wjH[m * 72 + k0] = h;
        *(u16x4*)&wjL[m * 72 + k0] = l;
    }

    // per-thread j-sum state
    int m  = tid & 63;
    int jc = tid >> 6;
    float ar_ = a_s[m + ((tid < 512) ? (tid & ~63) - (tid & ~63) : 0)]; (void)ar_;
    float ar[8], nar[8];
    v2f jacc[8];
#pragma unroll
    for (int r = 0; r < 8; ++r) {
        ar[r]   = a_s[r * 64 + m];
        nar[r]  = -ar[r];
        jacc[r] = (v2f){0.f, 0.f};
    }

    // MFMA geometry (per wave): wave w covers D rows m0..m0+15 (Wj-m), cols j0..j0+15 (V-j)
    int w  = tid >> 6;
    int m0 = (w >> 2) * 16, j0 = (w & 3) * 16;
    int lrow = lane & 15, lk = (lane >> 4) * 8;

    for (int jt = 0; jt < 8; ++jt) {
        __syncthreads();                     // vt free (prev MFMA done), c free for rewrite
        // stage V tile -> bf16 planes
        {
            int jl = tid >> 4, k0 = (tid & 15) << 2;
            float4 v4 = *(const float4*)&Vb[(jt * 64 + jl) * 64 + k0];
            u16x4 h, l; split4(v4, h, l);
            *(u16x4*)&vtH[jl * 72 + k0] = h;
            *(u16x4*)&vtL[jl * 72 + k0] = l;
        }
        __syncthreads();
        // MFMA: c[j][m] = Wj[m]·V[j] (3-term bf16 split), bake mask
        {
            const u16* aH = &wjH[(m0 + lrow) * 72 + lk];
            const u16* aL = &wjL[(m0 + lrow) * 72 + lk];
            const u16* bH = &vtH[(j0 + lrow) * 72 + lk];
            const u16* bL = &vtL[(j0 + lrow) * 72 + lk];
            f32x4 acc = {0.f, 0.f, 0.f, 0.f};
#pragma unroll
            for (int kh = 0; kh < 2; ++kh) {
                bf16x8 ah = *(const bf16x8*)(aH + kh * 32);
                bf16x8 al = *(const bf16x8*)(aL + kh * 32);
                bf16x8 bh = *(const bf16x8*)(bH + kh * 32);
                bf16x8 bl = *(const bf16x8*)(bL + kh * 32);
                acc = __builtin_amdgcn_mfma_f32_16x16x32_bf16(ah, bh, acc, 0, 0, 0);
                acc = __builtin_amdgcn_mfma_f32_16x16x32_bf16(ah, bl, acc, 0, 0, 0);
                acc = __builtin_amdgcn_mfma_f32_16x16x32_bf16(al, bh, acc, 0, 0, 0);
            }
            int jl  = j0 + (lane & 15);               // D col = lane&15 (verified m89)
            int sel = mask_s[jt * 64 + jl];
            f32x4 st;
#pragma unroll
            for (int i = 0; i < 4; ++i) st[i] = sel ? acc[i] : -1e30f;
            *(f32x4*)&cbuf[jl * 68 + m0 + (lane >> 4) * 4] = st;  // D row=(lane>>4)*4+i
        }
        __syncthreads();
        // j-sum over this tile's 64 j (4 per thread)
        {
            const float* cb0 = &cbuf[(jc * 4) * 68 + m];
#pragma unroll
            for (int p = 0; p < 2; ++p) {
                v2f c2 = { cb0[(2 * p) * 68], cb0[(2 * p + 1) * 68] };
#pragma unroll
                for (int r = 0; r < 8; ++r) {
                    v2f mx;
                    mx.x = fmaxf(c2.x, nar[r]);
                    mx.y = fmaxf(c2.y, nar[r]);
                    jacc[r] = pk_add(jacc[r], mx);
                }
            }
        }
    }

    // ---- epilogue ----
    __syncthreads();                         // all j-sums done; region0/1 reusable
#pragma unroll
    for (int r = 0; r < 8; ++r)
        part[jc * 512 + r * 64 + m] = jacc[r].x + jacc[r].y;
    {
        int oo = tid >> 4, kk = (tid & 15) << 2;
        *(float4*)&wn2[oo * 68 + kk] = *(const float4*)&Wn[oo * 128 + 64 + kk];
    }
    __syncthreads();

    if (tid < 512) {
        int r = tid >> 6;
        float aggsum = 0.f;
#pragma unroll
        for (int q = 0; q < 16; ++q) aggsum += part[q * 512 + tid];
        aggsum = fmaf(512.f, a_s[tid], aggsum);   // + 512*a (max-trick correction)
        agg_s[tid] = mk ? aggsum : 0.f;
    }
    __syncthreads();
    if (tid < 512) {
        int r = tid >> 6;
        float s = o1;
#pragma unroll
        for (int k = 0; k < 64; k += 4) {
            float4 h4 = *(float4*)&agg_s[r * 64 + k];   // wave-uniform broadcast
            float4 w4 = *(float4*)&wn2[m * 68 + k];
            s = fmaf(h4.x, w4.x, s); s = fmaf(h4.y, w4.y, s);
            s = fmaf(h4.z, w4.z, s); s = fmaf(h4.w, w4.w, s);
        }
        out[(i0 + r) * 64 + m] = fmaxf(s, 0.f);
    }
}

extern "C" void kernel_launch(void* const* d_in, const int* in_sizes, int n_in,
                              void* d_out, int out_size, void* d_ws, size_t ws_size,
                              hipStream_t stream) {
    const float* V    = (const float*)d_in[0];
    const int*   mask = (const int*)d_in[1];
    const float* Wmsg = (const float*)d_in[2];
    const float* bmsg = (const float*)d_in[3];
    const float* Wn   = (const float*)d_in[4];
    const float* bn   = (const float*)d_in[5];
    float* outp = (float*)d_out;

    const int BN = in_sizes[1];              // 2048
    fused_gb<<<dim3(BN / 8), dim3(1024), 0, stream>>>(V, mask, Wmsg, bmsg, Wn, bn, outp);
}

// Round 7
// 18.389 us; speedup vs baseline: 3.0602x; 1.0843x over previous
//
#include <hip/hip_runtime.h>
#include <hip/hip_bf16.h>

// B=4, N=512, D=64. ONE kernel, 256 blocks x 1024 thr (16 waves), no inter-block deps.
// All-MFMA design: c kept in accumulators (no LDS round-trip), j-sum in registers.
//   wave w: mh=w>>3 (m-half: m-tiles {2mh,2mh+1}), jg=w&7 (64 j's: 2 tiles/half-batch)
//   P1 (waves 0-3): a = bmsg + V8·Wi (2-term hi/lo), o1 = V8·Wn1 (regs), via MFMA
//   P2: vt = bf16(V half-batch) in XOR-swizzled LDS; acc=mfma(V_j, Wj_m);
//       p[r] += max(acc + maskf_j, -a[r][m])  (relu(a+c)=max(c,-a)+a; masked j: c-1e30 -> -a)
//   reduce: shfl_xor(16,32) -> part[8jg][8r][64m] -> agg = sum + 512*a, i-mask
//   epi (waves 0-3): out = relu(mfma(bf16(agg), Wn2, acc_o1) + bn)

typedef float  f32x4  __attribute__((ext_vector_type(4)));
typedef float  v2f    __attribute__((ext_vector_type(2)));
typedef short  bf16x8 __attribute__((ext_vector_type(8)));
typedef unsigned short u16;

__device__ __forceinline__ v2f pk_add(v2f a, v2f b) {
    v2f d; asm("v_pk_add_f32 %0, %1, %2" : "=v"(d) : "v"(a), "v"(b)); return d;
}
__device__ __forceinline__ u16 bf16_of(float x) {
    __hip_bfloat16 b = __float2bfloat16(x);
    return *(u16*)&b;
}
__device__ __forceinline__ bf16x8 cvt8(const float* p) {
    float4 x = *(const float4*)p, y = *(const float4*)(p + 4);
    float v[8] = {x.x, x.y, x.z, x.w, y.x, y.y, y.z, y.w};
    bf16x8 r;
#pragma unroll
    for (int i = 0; i < 8; ++i) r[i] = (short)bf16_of(v[i]);
    return r;
}
__device__ __forceinline__ void cvt8_hl(const float* p, bf16x8& h, bf16x8& l) {
    float4 x = *(const float4*)p, y = *(const float4*)(p + 4);
    float v[8] = {x.x, x.y, x.z, x.w, y.x, y.y, y.z, y.w};
#pragma unroll
    for (int i = 0; i < 8; ++i) {
        u16 hb = bf16_of(v[i]);
        h[i] = (short)hb;
        unsigned int u = (unsigned)hb << 16;
        l[i] = (short)bf16_of(v[i] - *(float*)&u);
    }
}

// LDS floats: vt u16[256][64] @0 (8192 f) | part f32[8][8][64] @0 overlay (4096 f)
//             maskf @8192 (512) | a_s[8][68] @8704 | agg_s[8][68] @9248  -> 9792 f = 39168 B
__global__ __launch_bounds__(1024) void fused_gb7(
    const float* __restrict__ V, const int* __restrict__ mask,
    const float* __restrict__ Wmsg, const float* __restrict__ bmsg,
    const float* __restrict__ Wn, const float* __restrict__ bn,
    float* __restrict__ out)
{
    __shared__ float buf[9792];
    u16*   vt    = (u16*)buf;
    float* part  = buf;
    float* maskf = buf + 8192;
    float* a_s   = buf + 8704;
    float* agg_s = buf + 9248;

    const int tid  = threadIdx.x;
    const int l    = tid & 63;
    const int w    = tid >> 6;
    const int g    = l >> 4;          // 0..3 k-group
    const int l15  = l & 15;
    const int mh   = w >> 3;          // 0..1
    const int jg   = w & 7;           // 0..7
    const int bb   = blockIdx.x >> 6; // batch
    const int i0   = blockIdx.x * 8;
    const int iloc = (blockIdx.x & 63) * 8;
    const float* Vb = V + (size_t)bb * 512 * 64;

    // ---- stage vt (half h): rows h*256..h*256+255 -> bf16, XOR-swizzled ----
    auto stage_half = [&](int h) {
#pragma unroll
        for (int q = 0; q < 4; ++q) {
            int idx = tid + q * 1024;            // 0..4095
            int row = idx >> 4;                  // 0..255
            int c4  = (idx & 15) << 2;           // float col 0,4,..,60
            float4 v4 = *(const float4*)&Vb[(h * 256 + row) * 64 + c4];
            ushort4 us;
            us.x = bf16_of(v4.x); us.y = bf16_of(v4.y);
            us.z = bf16_of(v4.z); us.w = bf16_of(v4.w);
            int byte = (row << 7) + (((c4 << 1)) ^ ((row & 7) << 4));
            *(ushort4*)((char*)vt + byte) = us;
        }
    };

    stage_half(0);
    if (tid < 512) maskf[tid] = mask[bb * 512 + tid] ? 0.f : -1e30f;

    // ---- Wj B-frags (all waves; per-wave constant) ----
    bf16x8 bWj[2][2];
#pragma unroll
    for (int mtp = 0; mtp < 2; ++mtp) {
        int mrow = (mh * 2 + mtp) * 16 + l15;
#pragma unroll
        for (int kh = 0; kh < 2; ++kh)
            bWj[mtp][kh] = cvt8(Wmsg + mrow * 128 + 64 + (g << 3) + (kh << 5));
    }

    // ---- P1: waves 0-3 compute a (hi/lo 2-term) and o1 via MFMA ----
    f32x4 acc_o1 = {0.f, 0.f, 0.f, 0.f};
    bf16x8 bWn2[2] = {};
    float bn_m = 0.f;
    if (w < 4) {
        bf16x8 aVh[2], aVl[2], bWih[2], bWil[2], bWn1[2];
#pragma unroll
        for (int kh = 0; kh < 2; ++kh) {
            cvt8_hl(V + (i0 + (l15 & 7)) * 64 + (g << 3) + (kh << 5), aVh[kh], aVl[kh]);
            cvt8_hl(Wmsg + (w * 16 + l15) * 128 + (g << 3) + (kh << 5), bWih[kh], bWil[kh]);
            bWn1[kh] = cvt8(Wn + (w * 16 + l15) * 128 + (g << 3) + (kh << 5));
            bWn2[kh] = cvt8(Wn + (w * 16 + l15) * 128 + 64 + (g << 3) + (kh << 5));
        }
        f32x4 acc_a = {0.f, 0.f, 0.f, 0.f};
#pragma unroll
        for (int kh = 0; kh < 2; ++kh) {
            acc_a = __builtin_amdgcn_mfma_f32_16x16x32_bf16(aVh[kh], bWih[kh], acc_a, 0, 0, 0);
            acc_a = __builtin_amdgcn_mfma_f32_16x16x32_bf16(aVl[kh], bWih[kh], acc_a, 0, 0, 0);
            acc_a = __builtin_amdgcn_mfma_f32_16x16x32_bf16(aVh[kh], bWil[kh], acc_a, 0, 0, 0);
            acc_o1 = __builtin_amdgcn_mfma_f32_16x16x32_bf16(aVh[kh], bWn1[kh], acc_o1, 0, 0, 0);
            acc_o1 = __builtin_amdgcn_mfma_f32_16x16x32_bf16(aVl[kh], bWn1[kh], acc_o1, 0, 0, 0);
        }
        float bm_m = bmsg[w * 16 + l15];
        bn_m = bn[w * 16 + l15];
        if (g < 2) {
#pragma unroll
            for (int i = 0; i < 4; ++i)
                a_s[(g * 4 + i) * 68 + w * 16 + l15] = acc_a[i] + bm_m;
        }
    }
    __syncthreads();                                      // S1: vt h0, maskf, a_s ready

    // nar per lane: 2 m's x 8 r
    float nar[2][8];
#pragma unroll
    for (int mtp = 0; mtp < 2; ++mtp) {
        int m = (mh * 2 + mtp) * 16 + l15;
#pragma unroll
        for (int r = 0; r < 8; ++r) nar[mtp][r] = -a_s[r * 68 + m];
    }
    v2f p2[2][8];
#pragma unroll
    for (int mtp = 0; mtp < 2; ++mtp)
#pragma unroll
        for (int r = 0; r < 8; ++r) p2[mtp][r] = (v2f){0.f, 0.f};

    auto compute_half = [&](int h) {
#pragma unroll
        for (int t = 0; t < 2; ++t) {
            int jbase = jg * 32 + t * 16;
            bf16x8 aV[2];
#pragma unroll
            for (int kh = 0; kh < 2; ++kh) {
                int jrow = jbase + l15;
                int byte = (jrow << 7) + ((((g << 4) + (kh << 6))) ^ ((jrow & 7) << 4));
                aV[kh] = *(const bf16x8*)((const char*)vt + byte);
            }
            f32x4 mf = *(const f32x4*)&maskf[h * 256 + jbase + g * 4];  // lane's 4 j's
#pragma unroll
            for (int mtp = 0; mtp < 2; ++mtp) {
                f32x4 acc = {0.f, 0.f, 0.f, 0.f};
                acc = __builtin_amdgcn_mfma_f32_16x16x32_bf16(aV[0], bWj[mtp][0], acc, 0, 0, 0);
                acc = __builtin_amdgcn_mfma_f32_16x16x32_bf16(aV[1], bWj[mtp][1], acc, 0, 0, 0);
                float cm0 = acc[0] + mf[0], cm1 = acc[1] + mf[1];
                float cm2 = acc[2] + mf[2], cm3 = acc[3] + mf[3];
#pragma unroll
                for (int r = 0; r < 8; ++r) {
                    float n = nar[mtp][r];
                    v2f mxa = { fmaxf(cm0, n), fmaxf(cm1, n) };
                    v2f mxb = { fmaxf(cm2, n), fmaxf(cm3, n) };
                    p2[mtp][r] = pk_add(p2[mtp][r], mxa);
                    p2[mtp][r] = pk_add(p2[mtp][r], mxb);
                }
            }
        }
    };

    compute_half(0);
    __syncthreads();                                      // S2: all vt h0 reads done
    stage_half(1);
    __syncthreads();                                      // S3: vt h1 ready
    compute_half(1);

    // in-wave reduction over g (lane^16, lane^32); l15/m preserved
    float pr[2][8];
#pragma unroll
    for (int mtp = 0; mtp < 2; ++mtp)
#pragma unroll
        for (int r = 0; r < 8; ++r) {
            float v = p2[mtp][r].x + p2[mtp][r].y;
            v += __shfl_xor(v, 16);
            v += __shfl_xor(v, 32);
            pr[mtp][r] = v;
        }
    __syncthreads();                                      // S4: vt reads done -> part overlay safe
    if (l < 16) {
#pragma unroll
        for (int mtp = 0; mtp < 2; ++mtp)
#pragma unroll
            for (int r = 0; r < 8; ++r)
                part[jg * 512 + r * 64 + (mh * 2 + mtp) * 16 + l15] = pr[mtp][r];
    }
    __syncthreads();                                      // S5: partials ready

    if (tid < 512) {
        int r = tid >> 6, m = tid & 63;
        float s = 0.f;
#pragma unroll
        for (int q = 0; q < 8; ++q) s += part[q * 512 + r * 64 + m];
        s = fmaf(512.f, a_s[r * 68 + m], s);              // max-trick correction
        s = (maskf[iloc + r] == 0.f) ? s : 0.f;           // i-mask
        agg_s[r * 68 + m] = s;
    }
    __syncthreads();                                      // S6: agg ready

    // ---- epilogue MFMA: out = relu(agg·Wn2 + o1 + bn) (waves 0-3) ----
    if (w < 4) {
        bf16x8 aAgg[2];
#pragma unroll
        for (int kh = 0; kh < 2; ++kh)
            aAgg[kh] = cvt8(&agg_s[(l15 & 7) * 68 + (g << 3) + (kh << 5)]);
        f32x4 accO = acc_o1;
        accO = __builtin_amdgcn_mfma_f32_16x16x32_bf16(aAgg[0], bWn2[0], accO, 0, 0, 0);
        accO = __builtin_amdgcn_mfma_f32_16x16x32_bf16(aAgg[1], bWn2[1], accO, 0, 0, 0);
        if (g < 2) {
#pragma unroll
            for (int i = 0; i < 4; ++i)
                out[(i0 + g * 4 + i) * 64 + w * 16 + l15] = fmaxf(accO[i] + bn_m, 0.f);
        }
    }
}

extern "C" void kernel_launch(void* const* d_in, const int* in_sizes, int n_in,
                              void* d_out, int out_size, void* d_ws, size_t ws_size,
                              hipStream_t stream) {
    const float* V    = (const float*)d_in[0];
    const int*   mask = (const int*)d_in[1];
    const float* Wmsg = (const float*)d_in[2];
    const float* bmsg = (const float*)d_in[3];
    const float* Wn   = (const float*)d_in[4];
    const float* bn   = (const float*)d_in[5];
    float* outp = (float*)d_out;

    const int BN = in_sizes[1];              // 2048
    fused_gb7<<<dim3(BN / 8), dim3(1024), 0, stream>>>(V, mask, Wmsg, bmsg, Wn, bn, outp);
}